// Round 8
// baseline (8244.318 us; speedup 1.0000x reference)
//
#include <hip/hip_runtime.h>
#include <hip/hip_bf16.h>

typedef __attribute__((ext_vector_type(8))) _Float16 f16x8;
typedef __attribute__((ext_vector_type(4))) float floatx4;

#define T_SEQ 512
#define B_SZ  64
#define I_SZ  512
#define H_SZ  1024
#define NC    3072
#define NGRP  4            // independent batch groups (16 batches each)
#define WPG   64           // WGs per group (16 columns each)
#define POISON_U 0x7E007E00u
#define MF(a,b,c) __builtin_amdgcn_mfma_f32_16x16x32_f16((a),(b),(c),0,0,0)

// ---------------- workspace layout (bytes) ----------------
// xproj fp16 [B*T][3072]                           : 201,326,592
// exc per group: H[2][16][1024] | R[2][16][1024]   : 4 * 131,072
//   (fp16, |values| < 1 always => 0x7E00 never occurs; used as in-band poison)
static const size_t XPROJ_BYTES = (size_t)B_SZ * T_SEQ * NC * 2;
static const size_t EXC_OFF = XPROJ_BYTES;

__device__ __forceinline__ f16x8 cvt8(float4 a, float4 b) {
  f16x8 v;
  v[0] = (_Float16)a.x; v[1] = (_Float16)a.y; v[2] = (_Float16)a.z; v[3] = (_Float16)a.w;
  v[4] = (_Float16)b.x; v[5] = (_Float16)b.y; v[6] = (_Float16)b.z; v[7] = (_Float16)b.w;
  return v;
}

// ---------------- init: H[1] = h0, H[0]/R[0]/R[1] = poison ----------------
__global__ void init_kernel(const float* __restrict__ h0, unsigned* __restrict__ exc) {
  int i = blockIdx.x * blockDim.x + threadIdx.x;   // 0 .. 4*4*8192-1 u32s
  if (i >= NGRP * 4 * 8192) return;
  int grp = i >> 15;
  int rem = i & 32767;
  int buf = rem >> 13;        // 0:H0 1:H1 2:R0 3:R1
  int wd  = rem & 8191;       // row = wd>>9 (16), wordcol = wd&511
  if (buf == 1) {
    int bl = wd >> 9, col2 = (wd & 511) * 2;
    int b = grp * 16 + bl;
    _Float16 lo = (_Float16)h0[(size_t)b * H_SZ + col2];
    _Float16 hi = (_Float16)h0[(size_t)b * H_SZ + col2 + 1];
    unsigned u = (unsigned)__builtin_bit_cast(unsigned short, lo) |
                 ((unsigned)__builtin_bit_cast(unsigned short, hi) << 16);
    exc[i] = u;
  } else {
    exc[i] = POISON_U;
  }
}

// ---------------- pre-GEMM: xproj = x @ Wx^T + bias (fp16, proven) ----------------
__global__ __launch_bounds__(256) void pregemm_kernel(
    const float* __restrict__ X, const float* __restrict__ Wrz,
    const float* __restrict__ Wh, const float* __restrict__ brz,
    const float* __restrict__ bh, _Float16* __restrict__ xproj) {
  __shared__ __align__(16) char smem[128 * 64 * 2];
  char* Asb = smem;
  char* Bsb = smem + 128 * 64;
  const int tid = threadIdx.x;
  const int w = tid >> 6, l = tid & 63;
  const int lg = l >> 4, ln = l & 15;
  const int wm = w >> 1, wn = w & 1;
  const int m0 = blockIdx.x * 128;
  const int n0 = blockIdx.y * 128;
  const int rs = tid >> 1;
  const int ks = (tid & 1) * 16;

  floatx4 acc[4][4];
#pragma unroll
  for (int i = 0; i < 4; i++)
#pragma unroll
    for (int j = 0; j < 4; j++) acc[i][j] = (floatx4){0.f, 0.f, 0.f, 0.f};

  const float* garow = X + (size_t)(m0 + rs) * I_SZ + ks;
  const int nrow = n0 + rs;
  const float* gbrow = (nrow < 2048) ? (Wrz + (size_t)nrow * 1536 + ks)
                                     : (Wh + (size_t)(nrow - 2048) * 1536 + ks);
  for (int kt = 0; kt < I_SZ; kt += 32) {
    float4 a0 = ((const float4*)(garow + kt))[0];
    float4 a1 = ((const float4*)(garow + kt))[1];
    float4 a2 = ((const float4*)(garow + kt))[2];
    float4 a3 = ((const float4*)(garow + kt))[3];
    float4 b0 = ((const float4*)(gbrow + kt))[0];
    float4 b1 = ((const float4*)(gbrow + kt))[1];
    float4 b2 = ((const float4*)(gbrow + kt))[2];
    float4 b3 = ((const float4*)(gbrow + kt))[3];
    __syncthreads();
    {
      int c0 = ks >> 3;
      f16x8* wp = (f16x8*)(Asb + rs * 64);
      wp[(c0)     ^ (rs & 3)] = cvt8(a0, a1);
      wp[(c0 + 1) ^ (rs & 3)] = cvt8(a2, a3);
      f16x8* wq = (f16x8*)(Bsb + rs * 64);
      wq[(c0)     ^ (rs & 3)] = cvt8(b0, b1);
      wq[(c0 + 1) ^ (rs & 3)] = cvt8(b2, b3);
    }
    __syncthreads();
    f16x8 af[4], bf[4];
#pragma unroll
    for (int i = 0; i < 4; i++) {
      int ra = wm * 64 + i * 16 + ln;
      af[i] = ((const f16x8*)(Asb + ra * 64))[lg ^ (ra & 3)];
      int rb = wn * 64 + i * 16 + ln;
      bf[i] = ((const f16x8*)(Bsb + rb * 64))[lg ^ (rb & 3)];
    }
#pragma unroll
    for (int i = 0; i < 4; i++)
#pragma unroll
      for (int j = 0; j < 4; j++)
        acc[i][j] = MF(af[i], bf[j], acc[i][j]);
  }
#pragma unroll
  for (int j = 0; j < 4; j++) {
    int n = n0 + wn * 64 + j * 16 + ln;
    float bias = (n < 2048) ? (brz[n] + ((n >= 1024) ? 1.0f : 0.0f)) : bh[n - 2048];
#pragma unroll
    for (int i = 0; i < 4; i++) {
      int mrow = m0 + wm * 64 + i * 16 + 4 * lg;
#pragma unroll
      for (int q = 0; q < 4; q++) {
        xproj[(size_t)(mrow + q) * NC + n] = (_Float16)(acc[i][j][q] + bias);
      }
    }
  }
}

// ---------------- batched 8 x 16B device-coherent loads (one wait) ----------------
#define ALD8(X, P) do { asm volatile( \
  "global_load_dwordx4 %0, %8, off sc0 sc1\n\t" \
  "global_load_dwordx4 %1, %8, off offset:64 sc0 sc1\n\t" \
  "global_load_dwordx4 %2, %8, off offset:128 sc0 sc1\n\t" \
  "global_load_dwordx4 %3, %8, off offset:192 sc0 sc1\n\t" \
  "global_load_dwordx4 %4, %8, off offset:256 sc0 sc1\n\t" \
  "global_load_dwordx4 %5, %8, off offset:320 sc0 sc1\n\t" \
  "global_load_dwordx4 %6, %8, off offset:384 sc0 sc1\n\t" \
  "global_load_dwordx4 %7, %8, off offset:448 sc0 sc1\n\t" \
  "s_waitcnt vmcnt(0)" \
  : "=&v"(X[0]), "=&v"(X[1]), "=&v"(X[2]), "=&v"(X[3]), \
    "=&v"(X[4]), "=&v"(X[5]), "=&v"(X[6]), "=&v"(X[7]) \
  : "v"(P) : "memory"); \
  __builtin_amdgcn_sched_barrier(0); } while (0)

// validate-read: retry until no u32 equals POISON (each u32 is store-atomic)
#define VLD8(X, P) do { \
  for (;;) { \
    ALD8(X, P); \
    unsigned bad_ = 0; \
    _Pragma("unroll") for (int i_ = 0; i_ < 8; ++i_) { \
      union { f16x8 v; unsigned u[4]; } x_; x_.v = X[i_]; \
      _Pragma("unroll") for (int k_ = 0; k_ < 4; ++k_) \
        bad_ |= (x_.u[k_] == POISON_U); \
    } \
    if (__all((int)(bad_ == 0))) break; \
  } } while (0)

// Pack (even,odd) column pair across lane pair via shfl, one u32 agent store.
__device__ __forceinline__ void pack_store_pair(unsigned* dst, int lane, int q,
                                                float v, size_t word) {
  _Float16 hh = (_Float16)v;
  unsigned short ms = __builtin_bit_cast(unsigned short, hh);
  unsigned ov = ((unsigned)__shfl_xor((int)ms, 1, 64)) & 0xffffu;
  unsigned wd = (lane & 1) ? (ov | ((unsigned)ms << 16)) : (((unsigned)ms) | (ov << 16));
  bool st = (q & 2) ? (bool)(lane & 1) : !(lane & 1);
  if (st)
    __hip_atomic_store(dst + word, wd, __ATOMIC_RELAXED, __HIP_MEMORY_SCOPE_AGENT);
}

// ---------------- persistent GRU: barrier-free in-band-validated exchange ----------------
__global__ __launch_bounds__(256) void gru_persistent_kernel(
    const float* __restrict__ Wrz, const float* __restrict__ Wh,
    const float* __restrict__ h0, const _Float16* __restrict__ xproj,
    float* __restrict__ Y, char* __restrict__ exc) {
  __shared__ __align__(16) char smem[48 * 2048 + 12288];  // weights | redR redZ redB
  floatx4* redR = (floatx4*)(smem + 98304);
  floatx4* redZ = redR + 256;
  floatx4* redB = redZ + 256;

  const int bid = blockIdx.x;
  const int grp = bid >> 6;
  const int c   = bid & 63;
  const int tid = threadIdx.x;
  const int w = tid >> 6, l = tid & 63;
  const int lg = l >> 4, ln = l & 15;
  const int sw = ln & 7;
  const int colbase = 16 * c;
  const int jg = colbase + ln;
  const int b0 = 16 * grp;

  // weights -> LDS: rows 0-15 r, 16-31 z, 32-47 h; k = 512..1535, XOR-swizzled
  for (int it = tid; it < 48 * 128; it += 256) {
    int r = it >> 7, cc = it & 127;
    const float* src;
    if (r < 16)      src = Wrz + (size_t)(colbase + r) * 1536 + 512 + cc * 8;
    else if (r < 32) src = Wrz + (size_t)(1024 + colbase + (r - 16)) * 1536 + 512 + cc * 8;
    else             src = Wh  + (size_t)(colbase + (r - 32)) * 1536 + 512 + cc * 8;
    float4 f0 = ((const float4*)src)[0];
    float4 f1 = ((const float4*)src)[1];
    ((f16x8*)(smem + (size_t)r * 2048))[cc ^ (r & 7)] = cvt8(f0, f1);
  }
  __syncthreads();

  const f16x8* bpr = (const f16x8*)(smem + (size_t)ln * 2048);
  const f16x8* bpz = (const f16x8*)(smem + (size_t)(16 + ln) * 2048);
  const f16x8* bph = (const f16x8*)(smem + (size_t)(32 + ln) * 2048);

  char* gb = exc + (size_t)grp * 131072;
  unsigned* Hw[2] = { (unsigned*)gb, (unsigned*)(gb + 32768) };
  unsigned* Rw[2] = { (unsigned*)(gb + 65536), (unsigned*)(gb + 98304) };

  // wave-0-only state
  float hm[4], zq[4], xr[4], xz[4], xh[4];
#define XPRE(T) { \
  _Pragma("unroll") for (int q_ = 0; q_ < 4; ++q_) { \
    size_t row_ = ((size_t)(b0 + 4 * lg + q_) * T_SEQ + (T)) * NC; \
    xr[q_] = (float)xproj[row_ + jg]; \
    xz[q_] = (float)xproj[row_ + 1024 + jg]; \
    xh[q_] = (float)xproj[row_ + 2048 + jg]; } }
  if (w == 0) {
#pragma unroll
    for (int q = 0; q < 4; ++q)
      hm[q] = h0[(size_t)(b0 + 4 * lg + q) * H_SZ + jg];
    XPRE(0)
  }

  const size_t rdoff = (size_t)ln * 1024 + 256 * w + 8 * lg;  // halves
  const int pw0 = (colbase >> 1);                              // poison stripe base word

  for (int t = 0; t < T_SEQ; ++t) {
    const int wp = t & 1, rp = wp ^ 1;
    // ---------------- phase A: r,z ----------------
    {
      f16x8 Af[8];
      const _Float16* pA = (const _Float16*)Hw[rp] + rdoff;
      VLD8(Af, pA);                    // waits for h_{t-1}; never sees stale data
      floatx4 ar = {0.f,0.f,0.f,0.f}, az = {0.f,0.f,0.f,0.f};
#pragma unroll
      for (int i = 0; i < 8; ++i) {
        int ki = 8 * w + i;
        ar = MF(Af[i], bpr[(4 * ki + lg) ^ sw], ar);
        az = MF(Af[i], bpz[(4 * ki + lg) ^ sw], az);
      }
      redR[tid] = ar;
      redZ[tid] = az;
    }
    __syncthreads();
    if (w == 0) {
      floatx4 Dr = redR[l] + redR[64 + l] + redR[128 + l] + redR[192 + l];
      floatx4 Dz = redZ[l] + redZ[64 + l] + redZ[128 + l] + redZ[192 + l];
      // poison H[wp] (all readers of it are provably done; rewritten in phase B)
#pragma unroll
      for (int k = 0; k < 2; ++k) {
        int idx = 64 * k + l;
        __hip_atomic_store(Hw[wp] + (idx >> 3) * 512 + pw0 + (idx & 7), POISON_U,
                           __ATOMIC_RELAXED, __HIP_MEMORY_SCOPE_AGENT);
      }
      float rh[4];
#pragma unroll
      for (int q = 0; q < 4; ++q) {
        float rr = 1.f / (1.f + __expf(-(Dr[q] + xr[q])));
        zq[q]    = 1.f / (1.f + __expf(-(Dz[q] + xz[q])));
        rh[q] = rr * hm[q];
      }
      asm volatile("s_waitcnt vmcnt(0)" ::: "memory");   // poison landed before data
#pragma unroll
      for (int q = 0; q < 4; ++q)
        pack_store_pair(Rw[wp], l, q, rh[q], (size_t)(4 * lg + q) * 512 + (jg >> 1));
    }
    // ---------------- phase B: hhat, h' ----------------
    {
      f16x8 Bf[8];
      const _Float16* pB = (const _Float16*)Rw[wp] + rdoff;
      VLD8(Bf, pB);                    // waits for rh_t (incl. own WG's wave-0 stores)
      floatx4 ah = {0.f,0.f,0.f,0.f};
#pragma unroll
      for (int i = 0; i < 8; ++i) {
        int ki = 8 * w + i;
        ah = MF(Bf[i], bph[(4 * ki + lg) ^ sw], ah);
      }
      redB[tid] = ah;
    }
    __syncthreads();
    if (w == 0) {
      floatx4 Dh = redB[l] + redB[64 + l] + redB[128 + l] + redB[192 + l];
      // poison R[rp] (read last step; rewritten next step's phase A)
#pragma unroll
      for (int k = 0; k < 2; ++k) {
        int idx = 64 * k + l;
        __hip_atomic_store(Rw[rp] + (idx >> 3) * 512 + pw0 + (idx & 7), POISON_U,
                           __ATOMIC_RELAXED, __HIP_MEMORY_SCOPE_AGENT);
      }
      float hnv[4];
#pragma unroll
      for (int q = 0; q < 4; ++q) {
        float hh = tanhf(Dh[q] + xh[q]);
        float hn = zq[q] * hm[q] + (1.f - zq[q]) * hh;
        hm[q] = hn; hnv[q] = hn;
      }
      asm volatile("s_waitcnt vmcnt(0)" ::: "memory");   // poison landed before data
#pragma unroll
      for (int q = 0; q < 4; ++q)
        pack_store_pair(Hw[wp], l, q, hnv[q], (size_t)(4 * lg + q) * 512 + (jg >> 1));
      // off critical path: output + next-step xproj prefetch
#pragma unroll
      for (int q = 0; q < 4; ++q)
        Y[((size_t)(b0 + 4 * lg + q) * T_SEQ + t) * H_SZ + jg] = hnv[q];
      if (t + 1 < T_SEQ) XPRE(t + 1)
    }
  }
}

// ---------------- launch ----------------
extern "C" void kernel_launch(void* const* d_in, const int* in_sizes, int n_in,
                              void* d_out, int out_size, void* d_ws, size_t ws_size,
                              hipStream_t stream) {
  const float* X   = (const float*)d_in[0];
  const float* h0  = (const float*)d_in[1];
  const float* Wrz = (const float*)d_in[2];
  const float* brz = (const float*)d_in[3];
  const float* Wh  = (const float*)d_in[4];
  const float* bh  = (const float*)d_in[5];
  float* Y = (float*)d_out;
  char* ws = (char*)d_ws;

  _Float16* xproj = (_Float16*)(ws);
  char*     exc   = ws + EXC_OFF;

  hipLaunchKernelGGL(init_kernel, dim3(512), dim3(256), 0, stream,
                     h0, (unsigned*)exc);
  hipLaunchKernelGGL(pregemm_kernel, dim3(256, 24), dim3(256), 0, stream,
                     X, Wrz, Wh, brz, bh, xproj);

  void* kargs[] = { (void*)&Wrz, (void*)&Wh, (void*)&h0, (void*)&xproj,
                    (void*)&Y, (void*)&exc };
  hipError_t ce = hipLaunchCooperativeKernel((void*)gru_persistent_kernel,
                                             dim3(NGRP * WPG), dim3(256), kargs, 0, stream);
  if (ce != hipSuccess) {
    // 256 WGs x ~108KB LDS = 1/CU on 256 CUs: co-resident under plain launch too
    hipLaunchKernelGGL(gru_persistent_kernel, dim3(NGRP * WPG), dim3(256), 0, stream,
                       Wrz, Wh, h0, xproj, Y, exc);
  }
}

// Round 9
// 7061.456 us; speedup vs baseline: 1.1675x; 1.1675x over previous
//
#include <hip/hip_runtime.h>
#include <hip/hip_bf16.h>

typedef __attribute__((ext_vector_type(8))) _Float16 f16x8;
typedef __attribute__((ext_vector_type(4))) float floatx4;

#define T_SEQ 512
#define B_SZ  64
#define I_SZ  512
#define H_SZ  1024
#define NC    3072
#define NGRP  4            // independent batch groups (16 batches each)
#define WPG   64           // WGs per group (16 columns each)
#define MF(a,b,c) __builtin_amdgcn_mfma_f32_16x16x32_f16((a),(b),(c),0,0,0)

// ---------------- workspace layout (bytes) ----------------
// xproj fp16 [B*T][3072]                       : 201,326,592
// exc per group: H kb-tiled | R kb-tiled       : 4 * 65,536
//   kb-tile layout: X[kb=0..31][batch=0..15][32 halves]  (1KB per kb-tile)
// flags u32 [4][64]                            : 1,024
static const size_t XPROJ_BYTES = (size_t)B_SZ * T_SEQ * NC * 2;
static const size_t EXC_OFF = XPROJ_BYTES;
static const size_t FLG_OFF = EXC_OFF + (size_t)NGRP * 65536;

__device__ __forceinline__ f16x8 cvt8(float4 a, float4 b) {
  f16x8 v;
  v[0] = (_Float16)a.x; v[1] = (_Float16)a.y; v[2] = (_Float16)a.z; v[3] = (_Float16)a.w;
  v[4] = (_Float16)b.x; v[5] = (_Float16)b.y; v[6] = (_Float16)b.z; v[7] = (_Float16)b.w;
  return v;
}

// ---------------- init: H (kb-tiled) = h0, flags = 0 ----------------
__global__ void init_kernel(const float* __restrict__ h0,
                            unsigned* __restrict__ exc,
                            unsigned* __restrict__ flags) {
  int i = blockIdx.x * blockDim.x + threadIdx.x;   // H words: 4 grp * 8192
  if (i < NGRP * 8192) {
    int grp = i >> 13;
    int wd  = i & 8191;
    int row = wd >> 4;            // kb*16 + b
    int kb = row >> 4, b = row & 15;
    int wcol = wd & 15;
    int k = kb * 32 + wcol * 2;
    int batch = grp * 16 + b;
    _Float16 lo = (_Float16)h0[(size_t)batch * H_SZ + k];
    _Float16 hi = (_Float16)h0[(size_t)batch * H_SZ + k + 1];
    unsigned u = (unsigned)__builtin_bit_cast(unsigned short, lo) |
                 ((unsigned)__builtin_bit_cast(unsigned short, hi) << 16);
    exc[(size_t)grp * 16384 + wd] = u;    // H at group base
  }
  if (i < NGRP * WPG) flags[i] = 0u;
}

// ---------------- pre-GEMM: xproj = x @ Wx^T + bias (fp16, proven) ----------------
__global__ __launch_bounds__(256) void pregemm_kernel(
    const float* __restrict__ X, const float* __restrict__ Wrz,
    const float* __restrict__ Wh, const float* __restrict__ brz,
    const float* __restrict__ bh, _Float16* __restrict__ xproj) {
  __shared__ __align__(16) char smem[128 * 64 * 2];
  char* Asb = smem;
  char* Bsb = smem + 128 * 64;
  const int tid = threadIdx.x;
  const int w = tid >> 6, l = tid & 63;
  const int lg = l >> 4, ln = l & 15;
  const int wm = w >> 1, wn = w & 1;
  const int m0 = blockIdx.x * 128;
  const int n0 = blockIdx.y * 128;
  const int rs = tid >> 1;
  const int ks = (tid & 1) * 16;

  floatx4 acc[4][4];
#pragma unroll
  for (int i = 0; i < 4; i++)
#pragma unroll
    for (int j = 0; j < 4; j++) acc[i][j] = (floatx4){0.f, 0.f, 0.f, 0.f};

  const float* garow = X + (size_t)(m0 + rs) * I_SZ + ks;
  const int nrow = n0 + rs;
  const float* gbrow = (nrow < 2048) ? (Wrz + (size_t)nrow * 1536 + ks)
                                     : (Wh + (size_t)(nrow - 2048) * 1536 + ks);
  for (int kt = 0; kt < I_SZ; kt += 32) {
    float4 a0 = ((const float4*)(garow + kt))[0];
    float4 a1 = ((const float4*)(garow + kt))[1];
    float4 a2 = ((const float4*)(garow + kt))[2];
    float4 a3 = ((const float4*)(garow + kt))[3];
    float4 b0 = ((const float4*)(gbrow + kt))[0];
    float4 b1 = ((const float4*)(gbrow + kt))[1];
    float4 b2 = ((const float4*)(gbrow + kt))[2];
    float4 b3 = ((const float4*)(gbrow + kt))[3];
    __syncthreads();
    {
      int c0 = ks >> 3;
      f16x8* wp = (f16x8*)(Asb + rs * 64);
      wp[(c0)     ^ (rs & 3)] = cvt8(a0, a1);
      wp[(c0 + 1) ^ (rs & 3)] = cvt8(a2, a3);
      f16x8* wq = (f16x8*)(Bsb + rs * 64);
      wq[(c0)     ^ (rs & 3)] = cvt8(b0, b1);
      wq[(c0 + 1) ^ (rs & 3)] = cvt8(b2, b3);
    }
    __syncthreads();
    f16x8 af[4], bf[4];
#pragma unroll
    for (int i = 0; i < 4; i++) {
      int ra = wm * 64 + i * 16 + ln;
      af[i] = ((const f16x8*)(Asb + ra * 64))[lg ^ (ra & 3)];
      int rb = wn * 64 + i * 16 + ln;
      bf[i] = ((const f16x8*)(Bsb + rb * 64))[lg ^ (rb & 3)];
    }
#pragma unroll
    for (int i = 0; i < 4; i++)
#pragma unroll
      for (int j = 0; j < 4; j++)
        acc[i][j] = MF(af[i], bf[j], acc[i][j]);
  }
#pragma unroll
  for (int j = 0; j < 4; j++) {
    int n = n0 + wn * 64 + j * 16 + ln;
    float bias = (n < 2048) ? (brz[n] + ((n >= 1024) ? 1.0f : 0.0f)) : bh[n - 2048];
#pragma unroll
    for (int i = 0; i < 4; i++) {
      int mrow = m0 + wm * 64 + i * 16 + 4 * lg;
#pragma unroll
      for (int q = 0; q < 4; q++) {
        xproj[(size_t)(mrow + q) * NC + n] = (_Float16)(acc[i][j][q] + bias);
      }
    }
  }
}

// ---- batched 8 x 16B coherent loads, fully coalesced (1KB/tile), 2 bases ----
#define ALD8C(X, P0, P1) do { asm volatile( \
  "global_load_dwordx4 %0, %8, off sc0 sc1\n\t" \
  "global_load_dwordx4 %1, %8, off offset:1024 sc0 sc1\n\t" \
  "global_load_dwordx4 %2, %8, off offset:2048 sc0 sc1\n\t" \
  "global_load_dwordx4 %3, %8, off offset:3072 sc0 sc1\n\t" \
  "global_load_dwordx4 %4, %9, off sc0 sc1\n\t" \
  "global_load_dwordx4 %5, %9, off offset:1024 sc0 sc1\n\t" \
  "global_load_dwordx4 %6, %9, off offset:2048 sc0 sc1\n\t" \
  "global_load_dwordx4 %7, %9, off offset:3072 sc0 sc1\n\t" \
  "s_waitcnt vmcnt(0)" \
  : "=&v"(X[0]), "=&v"(X[1]), "=&v"(X[2]), "=&v"(X[3]), \
    "=&v"(X[4]), "=&v"(X[5]), "=&v"(X[6]), "=&v"(X[7]) \
  : "v"(P0), "v"(P1) : "memory"); \
  __builtin_amdgcn_sched_barrier(0); } while (0)

// Pack (even,odd) column pair across lane pair via shfl, one u32 agent store.
__device__ __forceinline__ void pack_store_pair(unsigned* dst, int lane, int q,
                                                float v, size_t word) {
  _Float16 hh = (_Float16)v;
  unsigned short ms = __builtin_bit_cast(unsigned short, hh);
  unsigned ov = ((unsigned)__shfl_xor((int)ms, 1, 64)) & 0xffffu;
  unsigned wd = (lane & 1) ? (ov | ((unsigned)ms << 16)) : (((unsigned)ms) | (ov << 16));
  bool st = (q & 2) ? (bool)(lane & 1) : !(lane & 1);
  if (st)
    __hip_atomic_store(dst + word, wd, __ATOMIC_RELAXED, __HIP_MEMORY_SCOPE_AGENT);
}

// ---------------- persistent GRU: 4 grp x 64 WG x 256 thr, kb-tiled exchange ----------------
__global__ __launch_bounds__(256) void gru_persistent_kernel(
    const float* __restrict__ Wrz, const float* __restrict__ Wh,
    const float* __restrict__ h0, const _Float16* __restrict__ xproj,
    float* __restrict__ Y, char* __restrict__ exc,
    unsigned* __restrict__ flags) {
  __shared__ __align__(16) char smem[48 * 2048 + 8192];  // weights | redR redZ
  floatx4* redR = (floatx4*)(smem + 98304);
  floatx4* redZ = redR + 256;

  const int bid = blockIdx.x;
  const int grp = bid >> 6;
  const int c   = bid & 63;
  const int tid = threadIdx.x;
  const int w = tid >> 6, l = tid & 63;
  const int lg = l >> 4, ln = l & 15;
  const int sw = ln & 7;
  const int colbase = 16 * c;
  const int jg = colbase + ln;
  const int b0 = 16 * grp;

  // weights -> LDS: rows 0-15 r, 16-31 z, 32-47 h; k = 512..1535, XOR-swizzled
  for (int it = tid; it < 48 * 128; it += 256) {
    int r = it >> 7, cc = it & 127;
    const float* src;
    if (r < 16)      src = Wrz + (size_t)(colbase + r) * 1536 + 512 + cc * 8;
    else if (r < 32) src = Wrz + (size_t)(1024 + colbase + (r - 16)) * 1536 + 512 + cc * 8;
    else             src = Wh  + (size_t)(colbase + (r - 32)) * 1536 + 512 + cc * 8;
    float4 f0 = ((const float4*)src)[0];
    float4 f1 = ((const float4*)src)[1];
    ((f16x8*)(smem + (size_t)r * 2048))[cc ^ (r & 7)] = cvt8(f0, f1);
  }
  __syncthreads();

  const f16x8* bpr = (const f16x8*)(smem + (size_t)ln * 2048);
  const f16x8* bpz = (const f16x8*)(smem + (size_t)(16 + ln) * 2048);
  const f16x8* bph = (const f16x8*)(smem + (size_t)(32 + ln) * 2048);

  char* gb = exc + (size_t)grp * 65536;
  unsigned* Hw = (unsigned*)gb;              // kb-tiled H
  unsigned* Rw = (unsigned*)(gb + 32768);    // kb-tiled R
  unsigned* flg = flags + grp * WPG;

  // reader: wave w covers kb 8w..8w+7; lane (ln=batch, lg): tile offset ln*64 + lg*16
  const char* apA0 = gb         + (size_t)w * 8192 + ln * 64 + lg * 16;
  const char* apA1 = apA0 + 4096;
  const char* apB0 = gb + 32768 + (size_t)w * 8192 + ln * 64 + lg * 16;
  const char* apB1 = apB0 + 4096;

  // writer (wave 0): own 16 cols live in kb = c>>1, half (c&1)
  const int rowblk = (c >> 1) * 16;          // kb*16
  const int half8  = (c & 1) * 8 + (ln >> 1);

  // wave-0-only state
  float hm[4], zq[4], xr[4], xz[4], xh[4];
#define XPRE(T) { \
  _Pragma("unroll") for (int q_ = 0; q_ < 4; ++q_) { \
    size_t row_ = ((size_t)(b0 + 4 * lg + q_) * T_SEQ + (T)) * NC; \
    xr[q_] = (float)xproj[row_ + jg]; \
    xz[q_] = (float)xproj[row_ + 1024 + jg]; \
    xh[q_] = (float)xproj[row_ + 2048 + jg]; } }
  if (w == 0) {
#pragma unroll
    for (int q = 0; q < 4; ++q)
      hm[q] = h0[(size_t)(b0 + 4 * lg + q) * H_SZ + jg];
    XPRE(0)
  }

  unsigned bar = 0;
  for (int t = 0; t < T_SEQ; ++t) {
    // ---------------- phase A: r,z ----------------
    {
      f16x8 Af[8];
      ALD8C(Af, apA0, apA1);
      floatx4 ar = {0.f,0.f,0.f,0.f}, az = {0.f,0.f,0.f,0.f};
#pragma unroll
      for (int i = 0; i < 8; ++i) {
        int ki = 8 * w + i;
        ar = MF(Af[i], bpr[(4 * ki + lg) ^ sw], ar);
        az = MF(Af[i], bpz[(4 * ki + lg) ^ sw], az);
      }
      redR[tid] = ar;
      redZ[tid] = az;
    }
    __syncthreads();
    ++bar;
    if (w == 0) {
      floatx4 Dr = redR[l] + redR[64 + l] + redR[128 + l] + redR[192 + l];
      floatx4 Dz = redZ[l] + redZ[64 + l] + redZ[128 + l] + redZ[192 + l];
#pragma unroll
      for (int q = 0; q < 4; ++q) {
        float rr = 1.f / (1.f + __expf(-(Dr[q] + xr[q])));
        zq[q]    = 1.f / (1.f + __expf(-(Dz[q] + xz[q])));
        pack_store_pair(Rw, l, q, rr * hm[q],
                        (size_t)(rowblk + 4 * lg + q) * 16 + half8);
      }
      asm volatile("s_waitcnt vmcnt(0)" ::: "memory");
      if (tid == 0)
        __hip_atomic_store(&flg[c], bar, __ATOMIC_RELAXED, __HIP_MEMORY_SCOPE_AGENT);
    }
    {
      unsigned v;
      do { v = __hip_atomic_load(&flg[l], __ATOMIC_RELAXED, __HIP_MEMORY_SCOPE_AGENT); }
      while (__all((int)(v >= bar)) == 0);
    }
    // ---------------- phase B: hhat, h' ----------------
    {
      f16x8 Bf[8];
      ALD8C(Bf, apB0, apB1);
      floatx4 ah = {0.f,0.f,0.f,0.f};
#pragma unroll
      for (int i = 0; i < 8; ++i) {
        int ki = 8 * w + i;
        ah = MF(Bf[i], bph[(4 * ki + lg) ^ sw], ah);
      }
      redR[tid] = ah;
    }
    __syncthreads();
    ++bar;
    if (w == 0) {
      floatx4 Dh = redR[l] + redR[64 + l] + redR[128 + l] + redR[192 + l];
      float hnv[4];
#pragma unroll
      for (int q = 0; q < 4; ++q) {
        float hh = tanhf(Dh[q] + xh[q]);
        float hn = zq[q] * hm[q] + (1.f - zq[q]) * hh;
        hm[q] = hn; hnv[q] = hn;
        pack_store_pair(Hw, l, q, hn,
                        (size_t)(rowblk + 4 * lg + q) * 16 + half8);
      }
      asm volatile("s_waitcnt vmcnt(0)" ::: "memory");
      if (tid == 0)
        __hip_atomic_store(&flg[c], bar, __ATOMIC_RELAXED, __HIP_MEMORY_SCOPE_AGENT);
      // off critical path: output + next-step xproj prefetch ride under the wait
#pragma unroll
      for (int q = 0; q < 4; ++q)
        Y[((size_t)(b0 + 4 * lg + q) * T_SEQ + t) * H_SZ + jg] = hnv[q];
      if (t + 1 < T_SEQ) XPRE(t + 1)
    }
    {
      unsigned v;
      do { v = __hip_atomic_load(&flg[l], __ATOMIC_RELAXED, __HIP_MEMORY_SCOPE_AGENT); }
      while (__all((int)(v >= bar)) == 0);
    }
  }
}

// ---------------- launch ----------------
extern "C" void kernel_launch(void* const* d_in, const int* in_sizes, int n_in,
                              void* d_out, int out_size, void* d_ws, size_t ws_size,
                              hipStream_t stream) {
  const float* X   = (const float*)d_in[0];
  const float* h0  = (const float*)d_in[1];
  const float* Wrz = (const float*)d_in[2];
  const float* brz = (const float*)d_in[3];
  const float* Wh  = (const float*)d_in[4];
  const float* bh  = (const float*)d_in[5];
  float* Y = (float*)d_out;
  char* ws = (char*)d_ws;

  _Float16* xproj = (_Float16*)(ws);
  char*     exc   = ws + EXC_OFF;
  unsigned* flags = (unsigned*)(ws + FLG_OFF);

  hipLaunchKernelGGL(init_kernel, dim3(128), dim3(256), 0, stream,
                     h0, (unsigned*)exc, flags);
  hipLaunchKernelGGL(pregemm_kernel, dim3(256, 24), dim3(256), 0, stream,
                     X, Wrz, Wh, brz, bh, xproj);

  void* kargs[] = { (void*)&Wrz, (void*)&Wh, (void*)&h0, (void*)&xproj,
                    (void*)&Y, (void*)&exc, (void*)&flags };
  hipError_t ce = hipLaunchCooperativeKernel((void*)gru_persistent_kernel,
                                             dim3(NGRP * WPG), dim3(256), kargs, 0, stream);
  if (ce != hipSuccess) {
    hipLaunchKernelGGL(gru_persistent_kernel, dim3(NGRP * WPG), dim3(256), 0, stream,
                       Wrz, Wh, h0, xproj, Y, exc, flags);
  }
}

// Round 10
// 4283.324 us; speedup vs baseline: 1.9247x; 1.6486x over previous
//
#include <hip/hip_runtime.h>
#include <hip/hip_bf16.h>

typedef __attribute__((ext_vector_type(8))) _Float16 f16x8;
typedef __attribute__((ext_vector_type(4))) float floatx4;

#define T_SEQ 512
#define B_SZ  64
#define I_SZ  512
#define H_SZ  1024
#define NC    3072
#define NGRP  4            // independent batch groups (16 batches each)
#define WPG   64           // WGs per group (16 columns each)
#define MF(a,b,c) __builtin_amdgcn_mfma_f32_16x16x32_f16((a),(b),(c),0,0,0)

// ---------------- workspace layout (bytes) ----------------
// xproj fp16 [B*T][3072]                       : 201,326,592
// exc per group: H | R, each ctile-tiled       : 4 * 65,536
//   ctile layout: X[ct=0..63][batch=0..15][16 halves]  (512B per c-tile; WG c owns ct=c)
// flags u32 [4][64]                            : 1,024
static const size_t XPROJ_BYTES = (size_t)B_SZ * T_SEQ * NC * 2;
static const size_t EXC_OFF = XPROJ_BYTES;
static const size_t FLG_OFF = EXC_OFF + (size_t)NGRP * 65536;

__device__ __forceinline__ f16x8 cvt8(float4 a, float4 b) {
  f16x8 v;
  v[0] = (_Float16)a.x; v[1] = (_Float16)a.y; v[2] = (_Float16)a.z; v[3] = (_Float16)a.w;
  v[4] = (_Float16)b.x; v[5] = (_Float16)b.y; v[6] = (_Float16)b.z; v[7] = (_Float16)b.w;
  return v;
}

// ---------------- init: H (ctile-tiled) = h0, flags = 0 ----------------
__global__ void init_kernel(const float* __restrict__ h0,
                            unsigned* __restrict__ exc,
                            unsigned* __restrict__ flags) {
  int i = blockIdx.x * blockDim.x + threadIdx.x;   // H words: 4 grp * 8192
  if (i < NGRP * 8192) {
    int grp = i >> 13;
    int wd  = i & 8191;
    int hf  = wd * 2;                 // even half index
    int ct  = hf >> 8;
    int rem = hf & 255;
    int b   = rem >> 4, kin = rem & 15;
    int k   = ct * 16 + kin;
    int batch = grp * 16 + b;
    _Float16 lo = (_Float16)h0[(size_t)batch * H_SZ + k];
    _Float16 hi = (_Float16)h0[(size_t)batch * H_SZ + k + 1];
    unsigned u = (unsigned)__builtin_bit_cast(unsigned short, lo) |
                 ((unsigned)__builtin_bit_cast(unsigned short, hi) << 16);
    exc[(size_t)grp * 16384 + wd] = u;    // H at group base
  }
  if (i < NGRP * WPG) flags[i] = 0u;
}

// ---------------- pre-GEMM: xproj = x @ Wx^T + bias (fp16, proven) ----------------
__global__ __launch_bounds__(256) void pregemm_kernel(
    const float* __restrict__ X, const float* __restrict__ Wrz,
    const float* __restrict__ Wh, const float* __restrict__ brz,
    const float* __restrict__ bh, _Float16* __restrict__ xproj) {
  __shared__ __align__(16) char smem[128 * 64 * 2];
  char* Asb = smem;
  char* Bsb = smem + 128 * 64;
  const int tid = threadIdx.x;
  const int w = tid >> 6, l = tid & 63;
  const int lg = l >> 4, ln = l & 15;
  const int wm = w >> 1, wn = w & 1;
  const int m0 = blockIdx.x * 128;
  const int n0 = blockIdx.y * 128;
  const int rs = tid >> 1;
  const int ks = (tid & 1) * 16;

  floatx4 acc[4][4];
#pragma unroll
  for (int i = 0; i < 4; i++)
#pragma unroll
    for (int j = 0; j < 4; j++) acc[i][j] = (floatx4){0.f, 0.f, 0.f, 0.f};

  const float* garow = X + (size_t)(m0 + rs) * I_SZ + ks;
  const int nrow = n0 + rs;
  const float* gbrow = (nrow < 2048) ? (Wrz + (size_t)nrow * 1536 + ks)
                                     : (Wh + (size_t)(nrow - 2048) * 1536 + ks);
  for (int kt = 0; kt < I_SZ; kt += 32) {
    float4 a0 = ((const float4*)(garow + kt))[0];
    float4 a1 = ((const float4*)(garow + kt))[1];
    float4 a2 = ((const float4*)(garow + kt))[2];
    float4 a3 = ((const float4*)(garow + kt))[3];
    float4 b0 = ((const float4*)(gbrow + kt))[0];
    float4 b1 = ((const float4*)(gbrow + kt))[1];
    float4 b2 = ((const float4*)(gbrow + kt))[2];
    float4 b3 = ((const float4*)(gbrow + kt))[3];
    __syncthreads();
    {
      int c0 = ks >> 3;
      f16x8* wp = (f16x8*)(Asb + rs * 64);
      wp[(c0)     ^ (rs & 3)] = cvt8(a0, a1);
      wp[(c0 + 1) ^ (rs & 3)] = cvt8(a2, a3);
      f16x8* wq = (f16x8*)(Bsb + rs * 64);
      wq[(c0)     ^ (rs & 3)] = cvt8(b0, b1);
      wq[(c0 + 1) ^ (rs & 3)] = cvt8(b2, b3);
    }
    __syncthreads();
    f16x8 af[4], bf[4];
#pragma unroll
    for (int i = 0; i < 4; i++) {
      int ra = wm * 64 + i * 16 + ln;
      af[i] = ((const f16x8*)(Asb + ra * 64))[lg ^ (ra & 3)];
      int rb = wn * 64 + i * 16 + ln;
      bf[i] = ((const f16x8*)(Bsb + rb * 64))[lg ^ (rb & 3)];
    }
#pragma unroll
    for (int i = 0; i < 4; i++)
#pragma unroll
      for (int j = 0; j < 4; j++)
        acc[i][j] = MF(af[i], bf[j], acc[i][j]);
  }
#pragma unroll
  for (int j = 0; j < 4; j++) {
    int n = n0 + wn * 64 + j * 16 + ln;
    float bias = (n < 2048) ? (brz[n] + ((n >= 1024) ? 1.0f : 0.0f)) : bh[n - 2048];
#pragma unroll
    for (int i = 0; i < 4; i++) {
      int mrow = m0 + wm * 64 + i * 16 + 4 * lg;
#pragma unroll
      for (int q = 0; q < 4; q++) {
        xproj[(size_t)(mrow + q) * NC + n] = (_Float16)(acc[i][j][q] + bias);
      }
    }
  }
}

// ---- batched 8 x 16B coherent loads, fully coalesced, 2 bases (proven r9) ----
#define ALD8C(X, P0, P1) do { asm volatile( \
  "global_load_dwordx4 %0, %8, off sc0 sc1\n\t" \
  "global_load_dwordx4 %1, %8, off offset:1024 sc0 sc1\n\t" \
  "global_load_dwordx4 %2, %8, off offset:2048 sc0 sc1\n\t" \
  "global_load_dwordx4 %3, %8, off offset:3072 sc0 sc1\n\t" \
  "global_load_dwordx4 %4, %9, off sc0 sc1\n\t" \
  "global_load_dwordx4 %5, %9, off offset:1024 sc0 sc1\n\t" \
  "global_load_dwordx4 %6, %9, off offset:2048 sc0 sc1\n\t" \
  "global_load_dwordx4 %7, %9, off offset:3072 sc0 sc1\n\t" \
  "s_waitcnt vmcnt(0)" \
  : "=&v"(X[0]), "=&v"(X[1]), "=&v"(X[2]), "=&v"(X[3]), \
    "=&v"(X[4]), "=&v"(X[5]), "=&v"(X[6]), "=&v"(X[7]) \
  : "v"(P0), "v"(P1) : "memory"); \
  __builtin_amdgcn_sched_barrier(0); } while (0)

// one coherent 16B store (full-line batched across lanes)
#define AST16(P, V) asm volatile( \
  "global_store_dwordx4 %0, %1, off sc0 sc1" :: "v"(P), "v"(V) : "memory")

// ---------------- persistent GRU: r9 structure + full-line stores + LDS-done poll ----------------
__global__ __launch_bounds__(256) void gru_persistent_kernel(
    const float* __restrict__ Wrz, const float* __restrict__ Wh,
    const float* __restrict__ h0, const _Float16* __restrict__ xproj,
    float* __restrict__ Y, char* __restrict__ exc,
    unsigned* __restrict__ flags) {
  __shared__ __align__(16) char smem[48 * 2048 + 8192 + 1024];  // weights | redR redZ | stage+done
  floatx4* redR = (floatx4*)(smem + 98304);
  floatx4* redZ = redR + 256;
  unsigned short* sm16 = (unsigned short*)(smem + 106496);      // 512B transpose stage
  volatile unsigned* done_s = (volatile unsigned*)(smem + 107008);

  const int bid = blockIdx.x;
  const int grp = bid >> 6;
  const int c   = bid & 63;
  const int tid = threadIdx.x;
  const int w = tid >> 6, l = tid & 63;
  const int lg = l >> 4, ln = l & 15;
  const int sw = ln & 7;
  const int colbase = 16 * c;
  const int jg = colbase + ln;
  const int b0 = 16 * grp;

  if (tid == 0) *done_s = 0u;

  // weights -> LDS: rows 0-15 r, 16-31 z, 32-47 h; k = 512..1535, XOR-swizzled
  for (int it = tid; it < 48 * 128; it += 256) {
    int r = it >> 7, cc = it & 127;
    const float* src;
    if (r < 16)      src = Wrz + (size_t)(colbase + r) * 1536 + 512 + cc * 8;
    else if (r < 32) src = Wrz + (size_t)(1024 + colbase + (r - 16)) * 1536 + 512 + cc * 8;
    else             src = Wh  + (size_t)(colbase + (r - 32)) * 1536 + 512 + cc * 8;
    float4 f0 = ((const float4*)src)[0];
    float4 f1 = ((const float4*)src)[1];
    ((f16x8*)(smem + (size_t)r * 2048))[cc ^ (r & 7)] = cvt8(f0, f1);
  }
  __syncthreads();

  const f16x8* bpr = (const f16x8*)(smem + (size_t)ln * 2048);
  const f16x8* bpz = (const f16x8*)(smem + (size_t)(16 + ln) * 2048);
  const f16x8* bph = (const f16x8*)(smem + (size_t)(32 + ln) * 2048);

  char* gb = exc + (size_t)grp * 65536;
  unsigned* flg = flags + grp * WPG;

  // reader: frag (i) k = 256w + 32i + 8lg -> byte (16w+2i+(lg>>1))*512 + ln*32 + (lg&1)*16
  const char* apA0 = gb         + (size_t)w * 8192 + (lg >> 1) * 512 + ln * 32 + (lg & 1) * 16;
  const char* apA1 = apA0 + 4096;
  const char* apB0 = gb + 32768 + (size_t)w * 8192 + (lg >> 1) * 512 + ln * 32 + (lg & 1) * 16;
  const char* apB1 = apB0 + 4096;

  // writer: WG c owns c-tile c (512B); lanes l<32 store 16B each
  char* Hst = gb         + (size_t)c * 512 + l * 16;
  char* Rst = gb + 32768 + (size_t)c * 512 + l * 16;

  // wave-0-only state
  float hm[4], zq[4], xr[4], xz[4], xh[4];
#define XPRE(T) { \
  _Pragma("unroll") for (int q_ = 0; q_ < 4; ++q_) { \
    size_t row_ = ((size_t)(b0 + 4 * lg + q_) * T_SEQ + (T)) * NC; \
    xr[q_] = (float)xproj[row_ + jg]; \
    xz[q_] = (float)xproj[row_ + 1024 + jg]; \
    xh[q_] = (float)xproj[row_ + 2048 + jg]; } }
  if (w == 0) {
#pragma unroll
    for (int q = 0; q < 4; ++q)
      hm[q] = h0[(size_t)(b0 + 4 * lg + q) * H_SZ + jg];
    XPRE(0)
  }

  unsigned bar = 0;
  for (int t = 0; t < T_SEQ; ++t) {
    // ---------------- phase A: r,z ----------------
    {
      f16x8 Af[8];
      ALD8C(Af, apA0, apA1);
      floatx4 ar = {0.f,0.f,0.f,0.f}, az = {0.f,0.f,0.f,0.f};
#pragma unroll
      for (int i = 0; i < 8; ++i) {
        int ki = 8 * w + i;
        ar = MF(Af[i], bpr[(4 * ki + lg) ^ sw], ar);
        az = MF(Af[i], bpz[(4 * ki + lg) ^ sw], az);
      }
      redR[tid] = ar;
      redZ[tid] = az;
    }
    __syncthreads();
    ++bar;
    if (w == 0) {
      floatx4 Dr = redR[l] + redR[64 + l] + redR[128 + l] + redR[192 + l];
      floatx4 Dz = redZ[l] + redZ[64 + l] + redZ[128 + l] + redZ[192 + l];
#pragma unroll
      for (int q = 0; q < 4; ++q) {
        float rr = 1.f / (1.f + __expf(-(Dr[q] + xr[q])));
        zq[q]    = 1.f / (1.f + __expf(-(Dz[q] + xz[q])));
        _Float16 hh = (_Float16)(rr * hm[q]);
        sm16[(4 * lg + q) * 16 + ln] = __builtin_bit_cast(unsigned short, hh);
      }
      asm volatile("s_waitcnt lgkmcnt(0)" ::: "memory");
      __builtin_amdgcn_sched_barrier(0);
      if (l < 32) {
        f16x8 v = *(const f16x8*)(sm16 + l * 8);
        AST16(Rst, v);
      }
      asm volatile("s_waitcnt vmcnt(0)" ::: "memory");
      if (tid == 0)
        __hip_atomic_store(&flg[c], bar, __ATOMIC_RELAXED, __HIP_MEMORY_SCOPE_AGENT);
      unsigned v;
      do { v = __hip_atomic_load(&flg[l], __ATOMIC_RELAXED, __HIP_MEMORY_SCOPE_AGENT); }
      while (__all((int)(v >= bar)) == 0);
      *done_s = bar;
    } else {
      while (*done_s < bar) { }
    }
    // ---------------- phase B: hhat, h' ----------------
    {
      f16x8 Bf[8];
      ALD8C(Bf, apB0, apB1);
      floatx4 ah = {0.f,0.f,0.f,0.f};
#pragma unroll
      for (int i = 0; i < 8; ++i) {
        int ki = 8 * w + i;
        ah = MF(Bf[i], bph[(4 * ki + lg) ^ sw], ah);
      }
      redR[tid] = ah;
    }
    __syncthreads();
    ++bar;
    if (w == 0) {
      floatx4 Dh = redR[l] + redR[64 + l] + redR[128 + l] + redR[192 + l];
      float hnv[4];
#pragma unroll
      for (int q = 0; q < 4; ++q) {
        float hh = tanhf(Dh[q] + xh[q]);
        float hn = zq[q] * hm[q] + (1.f - zq[q]) * hh;
        hm[q] = hn; hnv[q] = hn;
        _Float16 hp = (_Float16)hn;
        sm16[(4 * lg + q) * 16 + ln] = __builtin_bit_cast(unsigned short, hp);
      }
      asm volatile("s_waitcnt lgkmcnt(0)" ::: "memory");
      __builtin_amdgcn_sched_barrier(0);
      if (l < 32) {
        f16x8 v = *(const f16x8*)(sm16 + l * 8);
        AST16(Hst, v);
      }
      asm volatile("s_waitcnt vmcnt(0)" ::: "memory");
      if (tid == 0)
        __hip_atomic_store(&flg[c], bar, __ATOMIC_RELAXED, __HIP_MEMORY_SCOPE_AGENT);
      // off critical path: output + next-step xproj prefetch ride under the wait
#pragma unroll
      for (int q = 0; q < 4; ++q)
        Y[((size_t)(b0 + 4 * lg + q) * T_SEQ + t) * H_SZ + jg] = hnv[q];
      if (t + 1 < T_SEQ) XPRE(t + 1)
      unsigned v;
      do { v = __hip_atomic_load(&flg[l], __ATOMIC_RELAXED, __HIP_MEMORY_SCOPE_AGENT); }
      while (__all((int)(v >= bar)) == 0);
      *done_s = bar;
    } else {
      while (*done_s < bar) { }
    }
  }
}

// ---------------- launch ----------------
extern "C" void kernel_launch(void* const* d_in, const int* in_sizes, int n_in,
                              void* d_out, int out_size, void* d_ws, size_t ws_size,
                              hipStream_t stream) {
  const float* X   = (const float*)d_in[0];
  const float* h0  = (const float*)d_in[1];
  const float* Wrz = (const float*)d_in[2];
  const float* brz = (const float*)d_in[3];
  const float* Wh  = (const float*)d_in[4];
  const float* bh  = (const float*)d_in[5];
  float* Y = (float*)d_out;
  char* ws = (char*)d_ws;

  _Float16* xproj = (_Float16*)(ws);
  char*     exc   = ws + EXC_OFF;
  unsigned* flags = (unsigned*)(ws + FLG_OFF);

  hipLaunchKernelGGL(init_kernel, dim3(128), dim3(256), 0, stream,
                     h0, (unsigned*)exc, flags);
  hipLaunchKernelGGL(pregemm_kernel, dim3(256, 24), dim3(256), 0, stream,
                     X, Wrz, Wh, brz, bh, xproj);

  void* kargs[] = { (void*)&Wrz, (void*)&Wh, (void*)&h0, (void*)&xproj,
                    (void*)&Y, (void*)&exc, (void*)&flags };
  hipError_t ce = hipLaunchCooperativeKernel((void*)gru_persistent_kernel,
                                             dim3(NGRP * WPG), dim3(256), kargs, 0, stream);
  if (ce != hipSuccess) {
    hipLaunchKernelGGL(gru_persistent_kernel, dim3(NGRP * WPG), dim3(256), 0, stream,
                       Wrz, Wh, h0, xproj, Y, exc, flags);
  }
}

// Round 11
// 3104.150 us; speedup vs baseline: 2.6559x; 1.3799x over previous
//
#include <hip/hip_runtime.h>
#include <hip/hip_bf16.h>

typedef __attribute__((ext_vector_type(8))) _Float16 f16x8;
typedef __attribute__((ext_vector_type(4))) float floatx4;

#define T_SEQ 512
#define B_SZ  64
#define I_SZ  512
#define H_SZ  1024
#define NC    3072
#define NGRP  4            // independent batch groups (16 batches each)
#define WPG   64           // WGs per group (16 columns each)
#define POISON_U 0x7E007E00u
#define MF(a,b,c) __builtin_amdgcn_mfma_f32_16x16x32_f16((a),(b),(c),0,0,0)

// ---------------- workspace layout (bytes) ----------------
// xproj fp16 [B*T][3072]                          : 201,326,592
// exc per group: H[2] | R[2], each ctile-tiled    : 4 * 131,072
//   ctile: X[ct=0..63][batch=0..15][16 halves] (512B/ctile; WG c owns ct=c)
//   |h|<1 and |r*h|<1 always => fp16 0x7E00 never occurs => in-band poison
static const size_t XPROJ_BYTES = (size_t)B_SZ * T_SEQ * NC * 2;
static const size_t EXC_OFF = XPROJ_BYTES;

__device__ __forceinline__ f16x8 cvt8(float4 a, float4 b) {
  f16x8 v;
  v[0] = (_Float16)a.x; v[1] = (_Float16)a.y; v[2] = (_Float16)a.z; v[3] = (_Float16)a.w;
  v[4] = (_Float16)b.x; v[5] = (_Float16)b.y; v[6] = (_Float16)b.z; v[7] = (_Float16)b.w;
  return v;
}

__device__ __forceinline__ f16x8 poison8() {
  union { unsigned u[4]; f16x8 v; } p;
  p.u[0] = p.u[1] = p.u[2] = p.u[3] = POISON_U;
  return p.v;
}

// ---------------- init: H1 (ctile) = h0; H0/R0/R1 = poison ----------------
__global__ void init_kernel(const float* __restrict__ h0, unsigned* __restrict__ exc) {
  int i = blockIdx.x * blockDim.x + threadIdx.x;   // NGRP * 32768 u32 words
  if (i >= NGRP * 32768) return;
  int grp = i >> 15;
  int wd  = i & 32767;
  int buf = wd >> 13;          // 0:H0 1:H1 2:R0 3:R1
  int wb  = wd & 8191;
  if (buf == 1) {
    int hf = wb * 2;
    int ct = hf >> 8, rem = hf & 255;
    int b = rem >> 4, kin = rem & 15;
    int k = ct * 16 + kin;
    int batch = grp * 16 + b;
    _Float16 lo = (_Float16)h0[(size_t)batch * H_SZ + k];
    _Float16 hi = (_Float16)h0[(size_t)batch * H_SZ + k + 1];
    exc[i] = (unsigned)__builtin_bit_cast(unsigned short, lo) |
             ((unsigned)__builtin_bit_cast(unsigned short, hi) << 16);
  } else {
    exc[i] = POISON_U;
  }
}

// ---------------- pre-GEMM: xproj = x @ Wx^T + bias (fp16, proven) ----------------
__global__ __launch_bounds__(256) void pregemm_kernel(
    const float* __restrict__ X, const float* __restrict__ Wrz,
    const float* __restrict__ Wh, const float* __restrict__ brz,
    const float* __restrict__ bh, _Float16* __restrict__ xproj) {
  __shared__ __align__(16) char smem[128 * 64 * 2];
  char* Asb = smem;
  char* Bsb = smem + 128 * 64;
  const int tid = threadIdx.x;
  const int w = tid >> 6, l = tid & 63;
  const int lg = l >> 4, ln = l & 15;
  const int wm = w >> 1, wn = w & 1;
  const int m0 = blockIdx.x * 128;
  const int n0 = blockIdx.y * 128;
  const int rs = tid >> 1;
  const int ks = (tid & 1) * 16;

  floatx4 acc[4][4];
#pragma unroll
  for (int i = 0; i < 4; i++)
#pragma unroll
    for (int j = 0; j < 4; j++) acc[i][j] = (floatx4){0.f, 0.f, 0.f, 0.f};

  const float* garow = X + (size_t)(m0 + rs) * I_SZ + ks;
  const int nrow = n0 + rs;
  const float* gbrow = (nrow < 2048) ? (Wrz + (size_t)nrow * 1536 + ks)
                                     : (Wh + (size_t)(nrow - 2048) * 1536 + ks);
  for (int kt = 0; kt < I_SZ; kt += 32) {
    float4 a0 = ((const float4*)(garow + kt))[0];
    float4 a1 = ((const float4*)(garow + kt))[1];
    float4 a2 = ((const float4*)(garow + kt))[2];
    float4 a3 = ((const float4*)(garow + kt))[3];
    float4 b0 = ((const float4*)(gbrow + kt))[0];
    float4 b1 = ((const float4*)(gbrow + kt))[1];
    float4 b2 = ((const float4*)(gbrow + kt))[2];
    float4 b3 = ((const float4*)(gbrow + kt))[3];
    __syncthreads();
    {
      int c0 = ks >> 3;
      f16x8* wp = (f16x8*)(Asb + rs * 64);
      wp[(c0)     ^ (rs & 3)] = cvt8(a0, a1);
      wp[(c0 + 1) ^ (rs & 3)] = cvt8(a2, a3);
      f16x8* wq = (f16x8*)(Bsb + rs * 64);
      wq[(c0)     ^ (rs & 3)] = cvt8(b0, b1);
      wq[(c0 + 1) ^ (rs & 3)] = cvt8(b2, b3);
    }
    __syncthreads();
    f16x8 af[4], bf[4];
#pragma unroll
    for (int i = 0; i < 4; i++) {
      int ra = wm * 64 + i * 16 + ln;
      af[i] = ((const f16x8*)(Asb + ra * 64))[lg ^ (ra & 3)];
      int rb = wn * 64 + i * 16 + ln;
      bf[i] = ((const f16x8*)(Bsb + rb * 64))[lg ^ (rb & 3)];
    }
#pragma unroll
    for (int i = 0; i < 4; i++)
#pragma unroll
      for (int j = 0; j < 4; j++)
        acc[i][j] = MF(af[i], bf[j], acc[i][j]);
  }
#pragma unroll
  for (int j = 0; j < 4; j++) {
    int n = n0 + wn * 64 + j * 16 + ln;
    float bias = (n < 2048) ? (brz[n] + ((n >= 1024) ? 1.0f : 0.0f)) : bh[n - 2048];
#pragma unroll
    for (int i = 0; i < 4; i++) {
      int mrow = m0 + wm * 64 + i * 16 + 4 * lg;
#pragma unroll
      for (int q = 0; q < 4; q++) {
        xproj[(size_t)(mrow + q) * NC + n] = (_Float16)(acc[i][j][q] + bias);
      }
    }
  }
}

// ---- batched 8 x 16B coherent loads, fully coalesced, 2 bases (proven r9/r10) ----
#define ALD8C(X, P0, P1) do { asm volatile( \
  "global_load_dwordx4 %0, %8, off sc0 sc1\n\t" \
  "global_load_dwordx4 %1, %8, off offset:1024 sc0 sc1\n\t" \
  "global_load_dwordx4 %2, %8, off offset:2048 sc0 sc1\n\t" \
  "global_load_dwordx4 %3, %8, off offset:3072 sc0 sc1\n\t" \
  "global_load_dwordx4 %4, %9, off sc0 sc1\n\t" \
  "global_load_dwordx4 %5, %9, off offset:1024 sc0 sc1\n\t" \
  "global_load_dwordx4 %6, %9, off offset:2048 sc0 sc1\n\t" \
  "global_load_dwordx4 %7, %9, off offset:3072 sc0 sc1\n\t" \
  "s_waitcnt vmcnt(0)" \
  : "=&v"(X[0]), "=&v"(X[1]), "=&v"(X[2]), "=&v"(X[3]), \
    "=&v"(X[4]), "=&v"(X[5]), "=&v"(X[6]), "=&v"(X[7]) \
  : "v"(P0), "v"(P1) : "memory"); \
  __builtin_amdgcn_sched_barrier(0); } while (0)

// validate-read: retry until no u32 is poison (proven r8 protocol)
#define VLD8C(X, P0, P1) do { \
  for (;;) { \
    ALD8C(X, P0, P1); \
    unsigned bad_ = 0; \
    _Pragma("unroll") for (int i_ = 0; i_ < 8; ++i_) { \
      union { f16x8 v; unsigned u[4]; } x_; x_.v = X[i_]; \
      _Pragma("unroll") for (int k_ = 0; k_ < 4; ++k_) \
        bad_ |= (x_.u[k_] == POISON_U); \
    } \
    if (__all((int)(bad_ == 0))) break; \
  } } while (0)

// one coherent 16B store
#define AST16(P, V) asm volatile( \
  "global_store_dwordx4 %0, %1, off sc0 sc1" :: "v"(P), "v"(V) : "memory")

// ---------------- persistent GRU: ctile layout + barrier-free poison exchange ----------------
__global__ __launch_bounds__(256) void gru_persistent_kernel(
    const float* __restrict__ Wrz, const float* __restrict__ Wh,
    const float* __restrict__ h0, const _Float16* __restrict__ xproj,
    float* __restrict__ Y, char* __restrict__ exc) {
  __shared__ __align__(16) char smem[48 * 2048 + 12288 + 512];  // weights | redR redZ redB | stage
  floatx4* redR = (floatx4*)(smem + 98304);
  floatx4* redZ = redR + 256;
  floatx4* redB = redZ + 256;
  unsigned short* sm16 = (unsigned short*)(smem + 110592);      // 512B transpose stage

  const int bid = blockIdx.x;
  const int grp = bid >> 6;
  const int c   = bid & 63;
  const int tid = threadIdx.x;
  const int w = tid >> 6, l = tid & 63;
  const int lg = l >> 4, ln = l & 15;
  const int sw = ln & 7;
  const int colbase = 16 * c;
  const int jg = colbase + ln;
  const int b0 = 16 * grp;

  // weights -> LDS: rows 0-15 r, 16-31 z, 32-47 h; k = 512..1535, XOR-swizzled
  for (int it = tid; it < 48 * 128; it += 256) {
    int r = it >> 7, cc = it & 127;
    const float* src;
    if (r < 16)      src = Wrz + (size_t)(colbase + r) * 1536 + 512 + cc * 8;
    else if (r < 32) src = Wrz + (size_t)(1024 + colbase + (r - 16)) * 1536 + 512 + cc * 8;
    else             src = Wh  + (size_t)(colbase + (r - 32)) * 1536 + 512 + cc * 8;
    float4 f0 = ((const float4*)src)[0];
    float4 f1 = ((const float4*)src)[1];
    ((f16x8*)(smem + (size_t)r * 2048))[cc ^ (r & 7)] = cvt8(f0, f1);
  }
  __syncthreads();

  const f16x8* bpr = (const f16x8*)(smem + (size_t)ln * 2048);
  const f16x8* bpz = (const f16x8*)(smem + (size_t)(16 + ln) * 2048);
  const f16x8* bph = (const f16x8*)(smem + (size_t)(32 + ln) * 2048);

  char* gb = exc + (size_t)grp * 131072;     // H0 | H1 | R0 | R1 (32KB each)

  // reader base: frag i -> byte (16w + 2i + (lg>>1))*512 + ln*32 + (lg&1)*16
  const size_t rbase = (size_t)w * 8192 + (lg >> 1) * 512 + ln * 32 + (lg & 1) * 16;
  // writer: WG c owns ctile c; lanes l<32 store 16B each
  const size_t wbase = (size_t)c * 512 + l * 16;

  const f16x8 pz = poison8();

  // wave-0-only state
  float hm[4], zq[4], xr[4], xz[4], xh[4];
#define XPRE(T) { \
  _Pragma("unroll") for (int q_ = 0; q_ < 4; ++q_) { \
    size_t row_ = ((size_t)(b0 + 4 * lg + q_) * T_SEQ + (T)) * NC; \
    xr[q_] = (float)xproj[row_ + jg]; \
    xz[q_] = (float)xproj[row_ + 1024 + jg]; \
    xh[q_] = (float)xproj[row_ + 2048 + jg]; } }
  if (w == 0) {
#pragma unroll
    for (int q = 0; q < 4; ++q)
      hm[q] = h0[(size_t)(b0 + 4 * lg + q) * H_SZ + jg];
    XPRE(0)
  }

  for (int t = 0; t < T_SEQ; ++t) {
    const size_t wpo = (size_t)(t & 1) * 32768;        // write-parity offset
    const size_t rpo = 32768 - wpo;                    // read-parity offset
    // ---------------- phase A: r,z ----------------
    {
      f16x8 Af[8];
      VLD8C(Af, gb + rpo + rbase, gb + rpo + rbase + 4096);   // h_{t-1}
      floatx4 ar = {0.f,0.f,0.f,0.f}, az = {0.f,0.f,0.f,0.f};
#pragma unroll
      for (int i = 0; i < 8; ++i) {
        int ki = 8 * w + i;
        ar = MF(Af[i], bpr[(4 * ki + lg) ^ sw], ar);
        az = MF(Af[i], bpz[(4 * ki + lg) ^ sw], az);
      }
      redR[tid] = ar;
      redZ[tid] = az;
    }
    __syncthreads();
    if (w == 0) {
      // poison H[wp] (safe: everyone finished reading it — r8 proof) before its phase-B rewrite
      if (l < 32) AST16(gb + wpo + wbase, pz);
      floatx4 Dr = redR[l] + redR[64 + l] + redR[128 + l] + redR[192 + l];
      floatx4 Dz = redZ[l] + redZ[64 + l] + redZ[128 + l] + redZ[192 + l];
#pragma unroll
      for (int q = 0; q < 4; ++q) {
        float rr = 1.f / (1.f + __expf(-(Dr[q] + xr[q])));
        zq[q]    = 1.f / (1.f + __expf(-(Dz[q] + xz[q])));
        _Float16 hh = (_Float16)(rr * hm[q]);
        sm16[(4 * lg + q) * 16 + ln] = __builtin_bit_cast(unsigned short, hh);
      }
      asm volatile("s_waitcnt lgkmcnt(0)" ::: "memory");
      __builtin_amdgcn_sched_barrier(0);
      if (l < 32) {
        f16x8 v = *(const f16x8*)(sm16 + l * 8);
        asm volatile("s_waitcnt vmcnt(0)" ::: "memory");   // poison at LIC before data
        AST16(gb + 65536 + wpo + wbase, v);                // R[wp] data = the sync signal
      }
    }
    // ---------------- phase B: hhat, h' ----------------
    {
      f16x8 Bf[8];
      VLD8C(Bf, gb + 65536 + wpo + rbase, gb + 65536 + wpo + rbase + 4096);  // rh_t
      floatx4 ah = {0.f,0.f,0.f,0.f};
#pragma unroll
      for (int i = 0; i < 8; ++i) {
        int ki = 8 * w + i;
        ah = MF(Bf[i], bph[(4 * ki + lg) ^ sw], ah);
      }
      redB[tid] = ah;
    }
    __syncthreads();
    if (w == 0) {
      // poison R[rp] (last read at step t-1 — r8 proof) before its next-step rewrite
      if (l < 32) AST16(gb + 65536 + rpo + wbase, pz);
      floatx4 Dh = redB[l] + redB[64 + l] + redB[128 + l] + redB[192 + l];
      float hnv[4];
#pragma unroll
      for (int q = 0; q < 4; ++q) {
        float hh = tanhf(Dh[q] + xh[q]);
        float hn = zq[q] * hm[q] + (1.f - zq[q]) * hh;
        hm[q] = hn; hnv[q] = hn;
        _Float16 hp = (_Float16)hn;
        sm16[(4 * lg + q) * 16 + ln] = __builtin_bit_cast(unsigned short, hp);
      }
      asm volatile("s_waitcnt lgkmcnt(0)" ::: "memory");
      __builtin_amdgcn_sched_barrier(0);
      if (l < 32) {
        f16x8 v = *(const f16x8*)(sm16 + l * 8);
        asm volatile("s_waitcnt vmcnt(0)" ::: "memory");   // poison at LIC before data
        AST16(gb + wpo + wbase, v);                        // H[wp] data = h_t
      }
      // off critical path: output + next-step xproj prefetch
#pragma unroll
      for (int q = 0; q < 4; ++q)
        Y[((size_t)(b0 + 4 * lg + q) * T_SEQ + t) * H_SZ + jg] = hnv[q];
      if (t + 1 < T_SEQ) XPRE(t + 1)
    }
  }
}

// ---------------- launch ----------------
extern "C" void kernel_launch(void* const* d_in, const int* in_sizes, int n_in,
                              void* d_out, int out_size, void* d_ws, size_t ws_size,
                              hipStream_t stream) {
  const float* X   = (const float*)d_in[0];
  const float* h0  = (const float*)d_in[1];
  const float* Wrz = (const float*)d_in[2];
  const float* brz = (const float*)d_in[3];
  const float* Wh  = (const float*)d_in[4];
  const float* bh  = (const float*)d_in[5];
  float* Y = (float*)d_out;
  char* ws = (char*)d_ws;

  _Float16* xproj = (_Float16*)(ws);
  char*     exc   = ws + EXC_OFF;

  hipLaunchKernelGGL(init_kernel, dim3(512), dim3(256), 0, stream,
                     h0, (unsigned*)exc);
  hipLaunchKernelGGL(pregemm_kernel, dim3(256, 24), dim3(256), 0, stream,
                     X, Wrz, Wh, brz, bh, xproj);

  void* kargs[] = { (void*)&Wrz, (void*)&Wh, (void*)&h0, (void*)&xproj,
                    (void*)&Y, (void*)&exc };
  hipError_t ce = hipLaunchCooperativeKernel((void*)gru_persistent_kernel,
                                             dim3(NGRP * WPG), dim3(256), kargs, 0, stream);
  if (ce != hipSuccess) {
    hipLaunchKernelGGL(gru_persistent_kernel, dim3(NGRP * WPG), dim3(256), 0, stream,
                       Wrz, Wh, h0, xproj, Y, exc);
  }
}

// Round 12
// 2971.410 us; speedup vs baseline: 2.7745x; 1.0447x over previous
//
#include <hip/hip_runtime.h>
#include <hip/hip_bf16.h>

typedef __attribute__((ext_vector_type(8))) _Float16 f16x8;
typedef __attribute__((ext_vector_type(4))) float floatx4;

#define T_SEQ 512
#define B_SZ  64
#define I_SZ  512
#define H_SZ  1024
#define NC    3072
#define NGRP  4            // independent batch groups (16 batches each)
#define WPG   64           // WGs per group (16 columns each)
#define POISON_U 0x7E007E00u
#define MF(a,b,c) __builtin_amdgcn_mfma_f32_16x16x32_f16((a),(b),(c),0,0,0)

// ---------------- workspace layout (bytes) ----------------
// xproj fp16 [B*T][3072]                          : 201,326,592
// exc per group: H[2] | R[2], each ctile-tiled    : 4 * 131,072
//   ctile: X[ct=0..63][batch=0..15][16 halves] (512B/ctile; WG c owns ct=c)
//   |h|<1 and |r*h|<1 always => fp16 0x7E00 never occurs => in-band poison
static const size_t XPROJ_BYTES = (size_t)B_SZ * T_SEQ * NC * 2;
static const size_t EXC_OFF = XPROJ_BYTES;

__device__ __forceinline__ f16x8 cvt8(float4 a, float4 b) {
  f16x8 v;
  v[0] = (_Float16)a.x; v[1] = (_Float16)a.y; v[2] = (_Float16)a.z; v[3] = (_Float16)a.w;
  v[4] = (_Float16)b.x; v[5] = (_Float16)b.y; v[6] = (_Float16)b.z; v[7] = (_Float16)b.w;
  return v;
}

__device__ __forceinline__ f16x8 poison8() {
  union { unsigned u[4]; f16x8 v; } p;
  p.u[0] = p.u[1] = p.u[2] = p.u[3] = POISON_U;
  return p.v;
}

// ---------------- init: H1 (ctile) = h0; H0/R0/R1 = poison ----------------
__global__ void init_kernel(const float* __restrict__ h0, unsigned* __restrict__ exc) {
  int i = blockIdx.x * blockDim.x + threadIdx.x;   // NGRP * 32768 u32 words
  if (i >= NGRP * 32768) return;
  int grp = i >> 15;
  int wd  = i & 32767;
  int buf = wd >> 13;          // 0:H0 1:H1 2:R0 3:R1
  int wb  = wd & 8191;
  if (buf == 1) {
    int hf = wb * 2;
    int ct = hf >> 8, rem = hf & 255;
    int b = rem >> 4, kin = rem & 15;
    int k = ct * 16 + kin;
    int batch = grp * 16 + b;
    _Float16 lo = (_Float16)h0[(size_t)batch * H_SZ + k];
    _Float16 hi = (_Float16)h0[(size_t)batch * H_SZ + k + 1];
    exc[i] = (unsigned)__builtin_bit_cast(unsigned short, lo) |
             ((unsigned)__builtin_bit_cast(unsigned short, hi) << 16);
  } else {
    exc[i] = POISON_U;
  }
}

// ---------------- pre-GEMM: xproj = x @ Wx^T + bias (fp16, proven) ----------------
__global__ __launch_bounds__(256) void pregemm_kernel(
    const float* __restrict__ X, const float* __restrict__ Wrz,
    const float* __restrict__ Wh, const float* __restrict__ brz,
    const float* __restrict__ bh, _Float16* __restrict__ xproj) {
  __shared__ __align__(16) char smem[128 * 64 * 2];
  char* Asb = smem;
  char* Bsb = smem + 128 * 64;
  const int tid = threadIdx.x;
  const int w = tid >> 6, l = tid & 63;
  const int lg = l >> 4, ln = l & 15;
  const int wm = w >> 1, wn = w & 1;
  const int m0 = blockIdx.x * 128;
  const int n0 = blockIdx.y * 128;
  const int rs = tid >> 1;
  const int ks = (tid & 1) * 16;

  floatx4 acc[4][4];
#pragma unroll
  for (int i = 0; i < 4; i++)
#pragma unroll
    for (int j = 0; j < 4; j++) acc[i][j] = (floatx4){0.f, 0.f, 0.f, 0.f};

  const float* garow = X + (size_t)(m0 + rs) * I_SZ + ks;
  const int nrow = n0 + rs;
  const float* gbrow = (nrow < 2048) ? (Wrz + (size_t)nrow * 1536 + ks)
                                     : (Wh + (size_t)(nrow - 2048) * 1536 + ks);
  for (int kt = 0; kt < I_SZ; kt += 32) {
    float4 a0 = ((const float4*)(garow + kt))[0];
    float4 a1 = ((const float4*)(garow + kt))[1];
    float4 a2 = ((const float4*)(garow + kt))[2];
    float4 a3 = ((const float4*)(garow + kt))[3];
    float4 b0 = ((const float4*)(gbrow + kt))[0];
    float4 b1 = ((const float4*)(gbrow + kt))[1];
    float4 b2 = ((const float4*)(gbrow + kt))[2];
    float4 b3 = ((const float4*)(gbrow + kt))[3];
    __syncthreads();
    {
      int c0 = ks >> 3;
      f16x8* wp = (f16x8*)(Asb + rs * 64);
      wp[(c0)     ^ (rs & 3)] = cvt8(a0, a1);
      wp[(c0 + 1) ^ (rs & 3)] = cvt8(a2, a3);
      f16x8* wq = (f16x8*)(Bsb + rs * 64);
      wq[(c0)     ^ (rs & 3)] = cvt8(b0, b1);
      wq[(c0 + 1) ^ (rs & 3)] = cvt8(b2, b3);
    }
    __syncthreads();
    f16x8 af[4], bf[4];
#pragma unroll
    for (int i = 0; i < 4; i++) {
      int ra = wm * 64 + i * 16 + ln;
      af[i] = ((const f16x8*)(Asb + ra * 64))[lg ^ (ra & 3)];
      int rb = wn * 64 + i * 16 + ln;
      bf[i] = ((const f16x8*)(Bsb + rb * 64))[lg ^ (rb & 3)];
    }
#pragma unroll
    for (int i = 0; i < 4; i++)
#pragma unroll
      for (int j = 0; j < 4; j++)
        acc[i][j] = MF(af[i], bf[j], acc[i][j]);
  }
#pragma unroll
  for (int j = 0; j < 4; j++) {
    int n = n0 + wn * 64 + j * 16 + ln;
    float bias = (n < 2048) ? (brz[n] + ((n >= 1024) ? 1.0f : 0.0f)) : bh[n - 2048];
#pragma unroll
    for (int i = 0; i < 4; i++) {
      int mrow = m0 + wm * 64 + i * 16 + 4 * lg;
#pragma unroll
      for (int q = 0; q < 4; q++) {
        xproj[(size_t)(mrow + q) * NC + n] = (_Float16)(acc[i][j][q] + bias);
      }
    }
  }
}

// ---- batched 8 x 16B coherent loads, fully coalesced, 2 bases (proven r9/r10) ----
#define ALD8C(X, P0, P1) do { asm volatile( \
  "global_load_dwordx4 %0, %8, off sc0 sc1\n\t" \
  "global_load_dwordx4 %1, %8, off offset:1024 sc0 sc1\n\t" \
  "global_load_dwordx4 %2, %8, off offset:2048 sc0 sc1\n\t" \
  "global_load_dwordx4 %3, %8, off offset:3072 sc0 sc1\n\t" \
  "global_load_dwordx4 %4, %9, off sc0 sc1\n\t" \
  "global_load_dwordx4 %5, %9, off offset:1024 sc0 sc1\n\t" \
  "global_load_dwordx4 %6, %9, off offset:2048 sc0 sc1\n\t" \
  "global_load_dwordx4 %7, %9, off offset:3072 sc0 sc1\n\t" \
  "s_waitcnt vmcnt(0)" \
  : "=&v"(X[0]), "=&v"(X[1]), "=&v"(X[2]), "=&v"(X[3]), \
    "=&v"(X[4]), "=&v"(X[5]), "=&v"(X[6]), "=&v"(X[7]) \
  : "v"(P0), "v"(P1) : "memory"); \
  __builtin_amdgcn_sched_barrier(0); } while (0)

// validate-read: retry until no u32 is poison (proven r8/r11 protocol)
#define VLD8C(X, P0, P1) do { \
  for (;;) { \
    ALD8C(X, P0, P1); \
    unsigned bad_ = 0; \
    _Pragma("unroll") for (int i_ = 0; i_ < 8; ++i_) { \
      union { f16x8 v; unsigned u[4]; } x_; x_.v = X[i_]; \
      _Pragma("unroll") for (int k_ = 0; k_ < 4; ++k_) \
        bad_ |= (x_.u[k_] == POISON_U); \
    } \
    if (__all((int)(bad_ == 0))) break; \
  } } while (0)

// one coherent 16B store
#define AST16(P, V) asm volatile( \
  "global_store_dwordx4 %0, %1, off sc0 sc1" :: "v"(P), "v"(V) : "memory")

// ---------------- persistent GRU: poison exchange, drains off wave0's path ----------------
// Poison schedule (safety chain re-derived, see commit message):
//   post-sync A(t): wave1 poisons R[wp(t+1)]  (ack absorbed by wave1's VLD-B(t))
//   post-sync B(t): wave2 poisons H[wp(t+1)]  (ack absorbed by wave2's VLD-A(t+1))
// Wave0's epilogue has NO poison stores and NO vmcnt drains.
__global__ __launch_bounds__(256) void gru_persistent_kernel(
    const float* __restrict__ Wrz, const float* __restrict__ Wh,
    const float* __restrict__ h0, const _Float16* __restrict__ xproj,
    float* __restrict__ Y, char* __restrict__ exc) {
  __shared__ __align__(16) char smem[48 * 2048 + 12288 + 512];  // weights | redR redZ redB | stage
  floatx4* redR = (floatx4*)(smem + 98304);
  floatx4* redZ = redR + 256;
  floatx4* redB = redZ + 256;
  unsigned short* sm16 = (unsigned short*)(smem + 110592);      // 512B transpose stage

  const int bid = blockIdx.x;
  const int grp = bid >> 6;
  const int c   = bid & 63;
  const int tid = threadIdx.x;
  const int w = tid >> 6, l = tid & 63;
  const int lg = l >> 4, ln = l & 15;
  const int sw = ln & 7;
  const int colbase = 16 * c;
  const int jg = colbase + ln;
  const int b0 = 16 * grp;

  // weights -> LDS: rows 0-15 r, 16-31 z, 32-47 h; k = 512..1535, XOR-swizzled
  for (int it = tid; it < 48 * 128; it += 256) {
    int r = it >> 7, cc = it & 127;
    const float* src;
    if (r < 16)      src = Wrz + (size_t)(colbase + r) * 1536 + 512 + cc * 8;
    else if (r < 32) src = Wrz + (size_t)(1024 + colbase + (r - 16)) * 1536 + 512 + cc * 8;
    else             src = Wh  + (size_t)(colbase + (r - 32)) * 1536 + 512 + cc * 8;
    float4 f0 = ((const float4*)src)[0];
    float4 f1 = ((const float4*)src)[1];
    ((f16x8*)(smem + (size_t)r * 2048))[cc ^ (r & 7)] = cvt8(f0, f1);
  }
  __syncthreads();

  const f16x8* bpr = (const f16x8*)(smem + (size_t)ln * 2048);
  const f16x8* bpz = (const f16x8*)(smem + (size_t)(16 + ln) * 2048);
  const f16x8* bph = (const f16x8*)(smem + (size_t)(32 + ln) * 2048);

  char* gb = exc + (size_t)grp * 131072;     // H0 | H1 | R0 | R1 (32KB each)

  // reader base: frag i -> byte (16w + 2i + (lg>>1))*512 + ln*32 + (lg&1)*16
  const size_t rbase = (size_t)w * 8192 + (lg >> 1) * 512 + ln * 32 + (lg & 1) * 16;
  // writer: WG c owns ctile c; lanes l<32 store 16B each
  const size_t wbase = (size_t)c * 512 + l * 16;

  const f16x8 pz = poison8();

  // wave-0-only state (zpre carries z pre-activation from phase A to B)
  float hm[4], zpre[4], xr[4], xz[4], xh[4];
#define XPRE(T) { \
  _Pragma("unroll") for (int q_ = 0; q_ < 4; ++q_) { \
    size_t row_ = ((size_t)(b0 + 4 * lg + q_) * T_SEQ + (T)) * NC; \
    xr[q_] = (float)xproj[row_ + jg]; \
    xz[q_] = (float)xproj[row_ + 1024 + jg]; \
    xh[q_] = (float)xproj[row_ + 2048 + jg]; } }
  if (w == 0) {
#pragma unroll
    for (int q = 0; q < 4; ++q)
      hm[q] = h0[(size_t)(b0 + 4 * lg + q) * H_SZ + jg];
    XPRE(0)
  }

  for (int t = 0; t < T_SEQ; ++t) {
    const size_t wpo = (size_t)(t & 1) * 32768;        // write-parity offset
    const size_t rpo = 32768 - wpo;                    // read-parity offset
    // ---------------- phase A: r (z deferred) ----------------
    {
      f16x8 Af[8];
      VLD8C(Af, gb + rpo + rbase, gb + rpo + rbase + 4096);   // h_{t-1}
      floatx4 ar = {0.f,0.f,0.f,0.f}, az = {0.f,0.f,0.f,0.f};
#pragma unroll
      for (int i = 0; i < 8; ++i) {
        int ki = 8 * w + i;
        ar = MF(Af[i], bpr[(4 * ki + lg) ^ sw], ar);
        az = MF(Af[i], bpz[(4 * ki + lg) ^ sw], az);
      }
      redR[tid] = ar;
      redZ[tid] = az;
    }
    __syncthreads();
    if (w == 0) {
      floatx4 Dr = redR[l] + redR[64 + l] + redR[128 + l] + redR[192 + l];
      floatx4 Dz = redZ[l] + redZ[64 + l] + redZ[128 + l] + redZ[192 + l];
#pragma unroll
      for (int q = 0; q < 4; ++q) {
        float rr = 1.f / (1.f + __expf(-(Dr[q] + xr[q])));
        zpre[q] = Dz[q] + xz[q];                       // sigmoid deferred to phase B
        _Float16 hh = (_Float16)(rr * hm[q]);
        sm16[(4 * lg + q) * 16 + ln] = __builtin_bit_cast(unsigned short, hh);
      }
      asm volatile("s_waitcnt lgkmcnt(0)" ::: "memory");
      __builtin_amdgcn_sched_barrier(0);
      if (l < 32) {
        f16x8 v = *(const f16x8*)(sm16 + l * 8);
        AST16(gb + 65536 + wpo + wbase, v);            // R[wp] data = the sync signal
      }
    } else if (w == 1) {
      // poison R[wp(t+1)] = R[rp-parity]: all reads of it (at B(t-1)) are provably done;
      // ack absorbed by this wave's VLD-B below, before B(t)'s sync -> ordered before
      // the H-stores that future R-readers chain through.
      if (l < 32) AST16(gb + 65536 + rpo + wbase, pz);
    }
    // ---------------- phase B: hhat, h' ----------------
    {
      f16x8 Bf[8];
      VLD8C(Bf, gb + 65536 + wpo + rbase, gb + 65536 + wpo + rbase + 4096);  // rh_t
      floatx4 ah = {0.f,0.f,0.f,0.f};
#pragma unroll
      for (int i = 0; i < 8; ++i) {
        int ki = 8 * w + i;
        ah = MF(Bf[i], bph[(4 * ki + lg) ^ sw], ah);
      }
      redB[tid] = ah;
    }
    __syncthreads();
    if (w == 0) {
      floatx4 Dh = redB[l] + redB[64 + l] + redB[128 + l] + redB[192 + l];
      float hnv[4];
#pragma unroll
      for (int q = 0; q < 4; ++q) {
        float z  = 1.f / (1.f + __expf(-zpre[q]));
        float hh = tanhf(Dh[q] + xh[q]);
        float hn = z * hm[q] + (1.f - z) * hh;
        hm[q] = hn; hnv[q] = hn;
        _Float16 hp = (_Float16)hn;
        sm16[(4 * lg + q) * 16 + ln] = __builtin_bit_cast(unsigned short, hp);
      }
      asm volatile("s_waitcnt lgkmcnt(0)" ::: "memory");
      __builtin_amdgcn_sched_barrier(0);
      if (l < 32) {
        f16x8 v = *(const f16x8*)(sm16 + l * 8);
        AST16(gb + wpo + wbase, v);                    // H[wp] data = h_t
      }
      // off critical path: output + next-step xproj prefetch
#pragma unroll
      for (int q = 0; q < 4; ++q)
        Y[((size_t)(b0 + 4 * lg + q) * T_SEQ + t) * H_SZ + jg] = hnv[q];
      if (t + 1 < T_SEQ) XPRE(t + 1)
    } else if (w == 2) {
      // poison H[wp(t+1)] = H[rp-parity]: all reads of it (at A(t)) are provably done;
      // ack absorbed by this wave's VLD-A(t+1), before A(t+1)'s sync -> ordered before
      // the R-stores that future H-readers chain through.
      if (l < 32) AST16(gb + rpo + wbase, pz);
    }
  }
}

// ---------------- launch ----------------
extern "C" void kernel_launch(void* const* d_in, const int* in_sizes, int n_in,
                              void* d_out, int out_size, void* d_ws, size_t ws_size,
                              hipStream_t stream) {
  const float* X   = (const float*)d_in[0];
  const float* h0  = (const float*)d_in[1];
  const float* Wrz = (const float*)d_in[2];
  const float* brz = (const float*)d_in[3];
  const float* Wh  = (const float*)d_in[4];
  const float* bh  = (const float*)d_in[5];
  float* Y = (float*)d_out;
  char* ws = (char*)d_ws;

  _Float16* xproj = (_Float16*)(ws);
  char*     exc   = ws + EXC_OFF;

  hipLaunchKernelGGL(init_kernel, dim3(512), dim3(256), 0, stream,
                     h0, (unsigned*)exc);
  hipLaunchKernelGGL(pregemm_kernel, dim3(256, 24), dim3(256), 0, stream,
                     X, Wrz, Wh, brz, bh, xproj);

  void* kargs[] = { (void*)&Wrz, (void*)&Wh, (void*)&h0, (void*)&xproj,
                    (void*)&Y, (void*)&exc };
  hipError_t ce = hipLaunchCooperativeKernel((void*)gru_persistent_kernel,
                                             dim3(NGRP * WPG), dim3(256), kargs, 0, stream);
  if (ce != hipSuccess) {
    hipLaunchKernelGGL(gru_persistent_kernel, dim3(NGRP * WPG), dim3(256), 0, stream,
                       Wrz, Wh, h0, xproj, Y, exc);
  }
}